// Round 1
// baseline (5072.033 us; speedup 1.0000x reference)
//
#include <hip/hip_runtime.h>

// Problem constants (match reference setup_inputs()).
constexpr int NA    = 200000;
constexpr int NW    = 50000;
constexpr int D     = 256;
constexpr int P     = 64;
constexpr int E_TIC = 4000000;
constexpr int E_REL = 1000000;

// ---------------------------------------------------------------------------
// Fused multi-weight GEMM: Y_m = X @ W_m for m in [0,NM), X:[N,256], W:[256,64].
// Block = 256 threads, computes 64 rows x 64 cols per weight matrix.
// LDS: transposed x chunk [32d][64r] (+pad) and W chunks [32d][64p].
// Each thread: 4x4 register micro-tile per matrix.
// ---------------------------------------------------------------------------
template <int NM>
__global__ __launch_bounds__(256) void gemm_fused(
    const float* __restrict__ x, int N,
    const float* __restrict__ W0, const float* __restrict__ W1,
    const float* __restrict__ W2,
    float* __restrict__ o0, float* __restrict__ o1, float* __restrict__ o2) {
  __shared__ float xT[32][68];        // [d][row], padded row (68*4B, 16B-aligned rows)
  __shared__ float Wc[NM][32][64];    // [m][d][p]

  const float* Wp[3] = {W0, W1, W2};
  float* op[3] = {o0, o1, o2};

  const int tid = threadIdx.x;
  const int tx = tid & 15;   // col group: cols tx*4 .. tx*4+3
  const int ty = tid >> 4;   // row group: rows ty*4 .. ty*4+3
  const int n0 = blockIdx.x * 64;

  float acc[NM][4][4];
#pragma unroll
  for (int m = 0; m < NM; ++m)
#pragma unroll
    for (int i = 0; i < 4; ++i)
#pragma unroll
      for (int j = 0; j < 4; ++j) acc[m][i][j] = 0.f;

  for (int kc = 0; kc < D / 32; ++kc) {
    // Stage x chunk (64 rows x 32 d), transposed into LDS.
#pragma unroll
    for (int i = 0; i < 2; ++i) {
      int f = tid + i * 256;          // float4 index within chunk [0,512)
      int row = f >> 3;               // 8 float4 per row
      int c4 = f & 7;
      int n = n0 + row;
      float4 v = make_float4(0.f, 0.f, 0.f, 0.f);
      if (n < N)
        v = *(const float4*)(x + (size_t)n * D + kc * 32 + c4 * 4);
      xT[c4 * 4 + 0][row] = v.x;
      xT[c4 * 4 + 1][row] = v.y;
      xT[c4 * 4 + 2][row] = v.z;
      xT[c4 * 4 + 3][row] = v.w;
    }
    // Stage W chunks (contiguous 32x64 fp32 per matrix).
#pragma unroll
    for (int m = 0; m < NM; ++m) {
#pragma unroll
      for (int i = 0; i < 2; ++i) {
        int f = tid + i * 256;
        ((float4*)&Wc[m][0][0])[f] =
            ((const float4*)(Wp[m] + kc * 32 * 64))[f];
      }
    }
    __syncthreads();

#pragma unroll 4
    for (int d = 0; d < 32; ++d) {
      float4 a4 = *(const float4*)&xT[d][ty * 4];
      float av[4] = {a4.x, a4.y, a4.z, a4.w};
#pragma unroll
      for (int m = 0; m < NM; ++m) {
        float4 b4 = *(const float4*)&Wc[m][d][tx * 4];
        float bv[4] = {b4.x, b4.y, b4.z, b4.w};
#pragma unroll
        for (int i = 0; i < 4; ++i)
#pragma unroll
          for (int j = 0; j < 4; ++j) acc[m][i][j] += av[i] * bv[j];
      }
    }
    __syncthreads();
  }

  // Store 4x4 micro-tiles.
#pragma unroll
  for (int m = 0; m < NM; ++m) {
#pragma unroll
    for (int i = 0; i < 4; ++i) {
      int n = n0 + ty * 4 + i;
      if (n < N) {
        float4 v = make_float4(acc[m][i][0], acc[m][i][1], acc[m][i][2],
                               acc[m][i][3]);
        *(float4*)(op[m] + (size_t)n * 64 + tx * 4) = v;
      }
    }
  }
}

// ---------------------------------------------------------------------------
// Edge scatter: acc[dst] += h[src] * w ; deg[dst] += 1.
// 16 threads per edge, float4 per thread, fp32 global atomics.
// ---------------------------------------------------------------------------
__global__ __launch_bounds__(256) void scatter_edges(
    const float* __restrict__ h, const int* __restrict__ src,
    const int* __restrict__ dst, const float* __restrict__ we,
    float* __restrict__ acc, float* __restrict__ deg, int E) {
  int t = blockIdx.x * 256 + threadIdx.x;
  int e = t >> 4;
  int l = t & 15;
  if (e >= E) return;
  int s = src[e];
  int d2 = dst[e];
  float w = we[e];
  float4 v = ((const float4*)h)[(size_t)s * 16 + l];
  float* ap = acc + (size_t)d2 * 64 + l * 4;
  atomicAdd(ap + 0, v.x * w);
  atomicAdd(ap + 1, v.y * w);
  atomicAdd(ap + 2, v.z * w);
  atomicAdd(ap + 3, v.w * w);
  if (l == 0) atomicAdd(deg + d2, 1.0f);
}

// ---------------------------------------------------------------------------
// h_ac = self(in out) + acc/deg + b
// ---------------------------------------------------------------------------
__global__ __launch_bounds__(256) void finalize_ac(
    float* __restrict__ out, const float* __restrict__ acc,
    const float* __restrict__ deg, const float* __restrict__ b) {
  int i4 = blockIdx.x * 256 + threadIdx.x;  // float4 index, < NA*16
  int n = i4 >> 4;
  int p4 = i4 & 15;
  float dg = deg[n];
  float inv = dg > 0.f ? 1.f / dg : 0.f;
  float4 o = ((float4*)out)[i4];
  float4 a = ((const float4*)acc)[i4];
  float4 bb = *(const float4*)(b + p4 * 4);
  o.x += a.x * inv + bb.x;
  o.y += a.y * inv + bb.y;
  o.z += a.z * inv + bb.z;
  o.w += a.w * inv + bb.w;
  ((float4*)out)[i4] = o;
}

// ---------------------------------------------------------------------------
// h_w = 0.5*(x_w[:, :64] + self(in out) + acc/deg + b)
// ---------------------------------------------------------------------------
__global__ __launch_bounds__(256) void finalize_w(
    float* __restrict__ out, const float* __restrict__ acc,
    const float* __restrict__ deg, const float* __restrict__ b,
    const float* __restrict__ xw) {
  int i4 = blockIdx.x * 256 + threadIdx.x;  // float4 index, < NW*16
  int n = i4 >> 4;
  int p4 = i4 & 15;
  float dg = deg[n];
  float inv = dg > 0.f ? 1.f / dg : 0.f;
  float4 h = ((float4*)out)[i4];
  float4 a = ((const float4*)acc)[i4];
  float4 bb = *(const float4*)(b + p4 * 4);
  float4 xv = *(const float4*)(xw + (size_t)n * D + p4 * 4);
  float4 r;
  r.x = 0.5f * (xv.x + h.x + a.x * inv + bb.x);
  r.y = 0.5f * (xv.y + h.y + a.y * inv + bb.y);
  r.z = 0.5f * (xv.z + h.z + a.z * inv + bb.z);
  r.w = 0.5f * (xv.w + h.w + a.w * inv + bb.w);
  ((float4*)out)[i4] = r;
}

extern "C" void kernel_launch(void* const* d_in, const int* in_sizes, int n_in,
                              void* d_out, int out_size, void* d_ws,
                              size_t ws_size, hipStream_t stream) {
  const float* x_ac  = (const float*)d_in[0];
  const float* x_w   = (const float*)d_in[1];
  const int*   src_t = (const int*)d_in[2];
  const int*   dst_t = (const int*)d_in[3];
  const float* w_t   = (const float*)d_in[4];
  const int*   src_r = (const int*)d_in[5];
  const int*   dst_r = (const int*)d_in[6];
  const float* w_r   = (const float*)d_in[7];
  const float* Wst   = (const float*)d_in[8];
  const float* Wnt   = (const float*)d_in[9];
  const float* bt    = (const float*)d_in[10];
  const float* Wsr   = (const float*)d_in[11];
  const float* Wnr   = (const float*)d_in[12];
  const float* br    = (const float*)d_in[13];

  float* out_ac = (float*)d_out;                      // [NA,64]
  float* out_w  = (float*)d_out + (size_t)NA * 64;    // [NW,64]

  // Workspace layout (floats).
  float* ws      = (float*)d_ws;
  float* h_tic   = ws;                                 // NA*64
  float* h_relm  = h_tic + (size_t)NA * 64;            // NA*64
  float* acc_tic = h_relm + (size_t)NA * 64;           // NA*64
  float* acc_rel = acc_tic + (size_t)NA * 64;          // NW*64
  float* deg_tic = acc_rel + (size_t)NW * 64;          // NA
  float* deg_rel = deg_tic + (size_t)NA;               // NW
  // (acc_tic .. deg_rel contiguous -> single memset)
  size_t zero_bytes = ((size_t)NA * 64 + (size_t)NW * 64 + NA + NW) * 4;
  hipMemsetAsync(acc_tic, 0, zero_bytes, stream);

  // Dense: self_tic -> out_ac, h_tic/h_relm -> ws (one pass over x_ac).
  gemm_fused<3><<<(NA + 63) / 64, 256, 0, stream>>>(
      x_ac, NA, Wst, Wnt, Wnr, out_ac, h_tic, h_relm);
  // Dense: self_rel -> out_w.
  gemm_fused<1><<<(NW + 63) / 64, 256, 0, stream>>>(
      x_w, NW, Wsr, nullptr, nullptr, out_w, nullptr, nullptr);

  // Sparse scatters.
  scatter_edges<<<(E_TIC * 16) / 256, 256, 0, stream>>>(
      h_tic, src_t, dst_t, w_t, acc_tic, deg_tic, E_TIC);
  scatter_edges<<<(E_REL * 16) / 256, 256, 0, stream>>>(
      h_relm, src_r, dst_r, w_r, acc_rel, deg_rel, E_REL);

  // Epilogues.
  finalize_ac<<<(NA * 16) / 256, 256, 0, stream>>>(out_ac, acc_tic, deg_tic, bt);
  finalize_w<<<(NW * 16) / 256, 256, 0, stream>>>(out_w, acc_rel, deg_rel, br, x_w);
}

// Round 2
// 1504.441 us; speedup vs baseline: 3.3714x; 3.3714x over previous
//
#include <hip/hip_runtime.h>

// Problem constants (match reference setup_inputs()).
constexpr int NA    = 200000;
constexpr int NW    = 50000;
constexpr int D     = 256;
constexpr int P     = 64;
constexpr int E_TIC = 4000000;
constexpr int E_REL = 1000000;
constexpr int NCAT  = NA + NW;                         // concatenated dst space
constexpr int SCAN_CHUNK = 2048;
constexpr int NBLK  = (NCAT + SCAN_CHUNK - 1) / SCAN_CHUNK;  // 123

// ---------------------------------------------------------------------------
// Fused multi-weight GEMM: Y_m = X @ W_m, X:[N,256], W:[256,64]. (unchanged)
// ---------------------------------------------------------------------------
template <int NM>
__global__ __launch_bounds__(256) void gemm_fused(
    const float* __restrict__ x, int N,
    const float* __restrict__ W0, const float* __restrict__ W1,
    const float* __restrict__ W2,
    float* __restrict__ o0, float* __restrict__ o1, float* __restrict__ o2) {
  __shared__ float xT[32][68];
  __shared__ float Wc[NM][32][64];

  const float* Wp[3] = {W0, W1, W2};
  float* op[3] = {o0, o1, o2};

  const int tid = threadIdx.x;
  const int tx = tid & 15;
  const int ty = tid >> 4;
  const int n0 = blockIdx.x * 64;

  float acc[NM][4][4];
#pragma unroll
  for (int m = 0; m < NM; ++m)
#pragma unroll
    for (int i = 0; i < 4; ++i)
#pragma unroll
      for (int j = 0; j < 4; ++j) acc[m][i][j] = 0.f;

  for (int kc = 0; kc < D / 32; ++kc) {
#pragma unroll
    for (int i = 0; i < 2; ++i) {
      int f = tid + i * 256;
      int row = f >> 3;
      int c4 = f & 7;
      int n = n0 + row;
      float4 v = make_float4(0.f, 0.f, 0.f, 0.f);
      if (n < N)
        v = *(const float4*)(x + (size_t)n * D + kc * 32 + c4 * 4);
      xT[c4 * 4 + 0][row] = v.x;
      xT[c4 * 4 + 1][row] = v.y;
      xT[c4 * 4 + 2][row] = v.z;
      xT[c4 * 4 + 3][row] = v.w;
    }
#pragma unroll
    for (int m = 0; m < NM; ++m) {
#pragma unroll
      for (int i = 0; i < 2; ++i) {
        int f = tid + i * 256;
        ((float4*)&Wc[m][0][0])[f] =
            ((const float4*)(Wp[m] + kc * 32 * 64))[f];
      }
    }
    __syncthreads();

#pragma unroll 4
    for (int d = 0; d < 32; ++d) {
      float4 a4 = *(const float4*)&xT[d][ty * 4];
      float av[4] = {a4.x, a4.y, a4.z, a4.w};
#pragma unroll
      for (int m = 0; m < NM; ++m) {
        float4 b4 = *(const float4*)&Wc[m][d][tx * 4];
        float bv[4] = {b4.x, b4.y, b4.z, b4.w};
#pragma unroll
        for (int i = 0; i < 4; ++i)
#pragma unroll
          for (int j = 0; j < 4; ++j) acc[m][i][j] += av[i] * bv[j];
      }
    }
    __syncthreads();
  }

#pragma unroll
  for (int m = 0; m < NM; ++m) {
#pragma unroll
    for (int i = 0; i < 4; ++i) {
      int n = n0 + ty * 4 + i;
      if (n < N) {
        float4 v = make_float4(acc[m][i][0], acc[m][i][1], acc[m][i][2],
                               acc[m][i][3]);
        *(float4*)(op[m] + (size_t)n * 64 + tx * 4) = v;
      }
    }
  }
}

// ---------------------------------------------------------------------------
// CSR build step 1: degree histogram (int atomics into concatenated space).
// ---------------------------------------------------------------------------
__global__ __launch_bounds__(256) void count_deg(const int* __restrict__ dst,
                                                 int* __restrict__ deg, int E,
                                                 int base) {
  int i = blockIdx.x * 256 + threadIdx.x;
  if (i < E) atomicAdd(&deg[base + dst[i]], 1);
}

// ---------------------------------------------------------------------------
// CSR build step 2: exclusive prefix scan over deg_cat[NCAT] -> rp[NCAT].
// Three small kernels: per-block scan (2048/block), scan of block sums, add.
// ---------------------------------------------------------------------------
__global__ __launch_bounds__(256) void scan_block(const int* __restrict__ deg,
                                                  int* __restrict__ rp,
                                                  int* __restrict__ bsum) {
  __shared__ int lds[256];
  int b = blockIdx.x, t = threadIdx.x;
  int base = b * SCAN_CHUNK + t * 8;
  int v[8];
#pragma unroll
  for (int j = 0; j < 8; ++j) {
    int idx = base + j;
    v[j] = (idx < NCAT) ? deg[idx] : 0;
  }
  int s = 0;
#pragma unroll
  for (int j = 0; j < 8; ++j) {
    int tmp = v[j];
    v[j] = s;          // exclusive within thread
    s += tmp;
  }
  lds[t] = s;
  __syncthreads();
  // inclusive Hillis-Steele over 256 thread totals
  for (int off = 1; off < 256; off <<= 1) {
    int x = (t >= off) ? lds[t - off] : 0;
    __syncthreads();
    lds[t] += x;
    __syncthreads();
  }
  int excl = (t == 0) ? 0 : lds[t - 1];
  if (t == 255) bsum[b] = lds[255];
#pragma unroll
  for (int j = 0; j < 8; ++j) {
    int idx = base + j;
    if (idx < NCAT) rp[idx] = excl + v[j];
  }
}

__global__ __launch_bounds__(256) void scan_bsum(int* __restrict__ bsum) {
  __shared__ int lds[256];
  int t = threadIdx.x;
  lds[t] = (t < NBLK) ? bsum[t] : 0;
  __syncthreads();
  for (int off = 1; off < 256; off <<= 1) {
    int x = (t >= off) ? lds[t - off] : 0;
    __syncthreads();
    lds[t] += x;
    __syncthreads();
  }
  int excl = (t == 0) ? 0 : lds[t - 1];
  if (t < NBLK) bsum[t] = excl;
}

__global__ __launch_bounds__(256) void scan_add(int* __restrict__ rp,
                                                const int* __restrict__ bsum) {
  int i = blockIdx.x * 256 + threadIdx.x;
  if (i < NCAT) rp[i] += bsum[i >> 11];
}

// ---------------------------------------------------------------------------
// CSR build step 3: fill. pos = rp[d]++ (atomic); edges[pos] = {src, w}.
// After this kernel rp[d] == row END; start = rp[d] - deg[d].
// ---------------------------------------------------------------------------
__global__ __launch_bounds__(256) void fill_edges(
    const int* __restrict__ src, const int* __restrict__ dst,
    const float* __restrict__ w, int* __restrict__ rp,
    int2* __restrict__ edges, int E, int base) {
  int e = blockIdx.x * 256 + threadIdx.x;
  if (e >= E) return;
  int d = base + dst[e];
  int pos = atomicAdd(&rp[d], 1);
  edges[pos] = make_int2(src[e], __float_as_int(w[e]));
}

// ---------------------------------------------------------------------------
// Pull aggregation + fused epilogue. One wave (64 lanes) per dst node; lane =
// output channel. Each edge -> one coalesced 256 B read of h[src].
//   WORD=false: out[n] += sum/deg + b            (acoustic)
//   WORD=true : out[n] = 0.5*(xw[n,:64] + out[n] + sum/deg + b)
// ---------------------------------------------------------------------------
template <bool WORD>
__global__ __launch_bounds__(256) void pull_nodes(
    const float* __restrict__ h, const int2* __restrict__ edges,
    const int* __restrict__ rp, const int* __restrict__ deg,
    const float* __restrict__ b, const float* __restrict__ xw,
    float* __restrict__ out, int N, int base) {
  int wave = (blockIdx.x * 256 + threadIdx.x) >> 6;
  int lane = threadIdx.x & 63;
  if (wave >= N) return;
  int n = wave;
  int end = rp[base + n];          // row end (post-fill)
  int cnt = deg[base + n];
  int start = end - cnt;

  float acc = 0.f;
  for (int c = start; c < end; c += 64) {
    int2 ed = make_int2(0, 0);
    int idx = c + lane;
    if (idx < end) ed = edges[idx];
    int m = min(64, end - c);
    for (int j = 0; j < m; ++j) {
      int s = __shfl(ed.x, j);
      float wv = __int_as_float(__shfl(ed.y, j));
      acc += h[(size_t)s * 64 + lane] * wv;
    }
  }
  float neigh = cnt > 0 ? acc / (float)cnt : 0.f;
  float bias = b[lane];
  size_t oi = (size_t)n * 64 + lane;
  if (!WORD) {
    out[oi] += neigh + bias;
  } else {
    out[oi] = 0.5f * (xw[(size_t)n * D + lane] + out[oi] + neigh + bias);
  }
}

extern "C" void kernel_launch(void* const* d_in, const int* in_sizes, int n_in,
                              void* d_out, int out_size, void* d_ws,
                              size_t ws_size, hipStream_t stream) {
  const float* x_ac  = (const float*)d_in[0];
  const float* x_w   = (const float*)d_in[1];
  const int*   src_t = (const int*)d_in[2];
  const int*   dst_t = (const int*)d_in[3];
  const float* w_t   = (const float*)d_in[4];
  const int*   src_r = (const int*)d_in[5];
  const int*   dst_r = (const int*)d_in[6];
  const float* w_r   = (const float*)d_in[7];
  const float* Wst   = (const float*)d_in[8];
  const float* Wnt   = (const float*)d_in[9];
  const float* bt    = (const float*)d_in[10];
  const float* Wsr   = (const float*)d_in[11];
  const float* Wnr   = (const float*)d_in[12];
  const float* br    = (const float*)d_in[13];

  float* out_ac = (float*)d_out;                      // [NA,64]
  float* out_w  = (float*)d_out + (size_t)NA * 64;    // [NW,64]

  // Workspace layout.
  float* ws     = (float*)d_ws;
  float* h_tic  = ws;                                 // NA*64 floats
  float* h_relm = h_tic + (size_t)NA * 64;            // NA*64 floats
  int2*  edges  = (int2*)(h_relm + (size_t)NA * 64);  // (E_TIC+E_REL) int2
  int*   deg    = (int*)(edges + (size_t)(E_TIC + E_REL));  // NCAT ints
  int*   rp     = deg + NCAT;                         // NCAT ints
  int*   bsum   = rp + NCAT;                          // NBLK ints

  hipMemsetAsync(deg, 0, (size_t)NCAT * 4, stream);

  // Dense: self_tic -> out_ac, h_tic/h_relm -> ws (one pass over x_ac).
  gemm_fused<3><<<(NA + 63) / 64, 256, 0, stream>>>(
      x_ac, NA, Wst, Wnt, Wnr, out_ac, h_tic, h_relm);
  gemm_fused<1><<<(NW + 63) / 64, 256, 0, stream>>>(
      x_w, NW, Wsr, nullptr, nullptr, out_w, nullptr, nullptr);

  // CSR build.
  count_deg<<<(E_TIC + 255) / 256, 256, 0, stream>>>(dst_t, deg, E_TIC, 0);
  count_deg<<<(E_REL + 255) / 256, 256, 0, stream>>>(dst_r, deg, E_REL, NA);
  scan_block<<<NBLK, 256, 0, stream>>>(deg, rp, bsum);
  scan_bsum<<<1, 256, 0, stream>>>(bsum);
  scan_add<<<(NCAT + 255) / 256, 256, 0, stream>>>(rp, bsum);
  fill_edges<<<(E_TIC + 255) / 256, 256, 0, stream>>>(src_t, dst_t, w_t, rp,
                                                      edges, E_TIC, 0);
  fill_edges<<<(E_REL + 255) / 256, 256, 0, stream>>>(src_r, dst_r, w_r, rp,
                                                      edges, E_REL, NA);

  // Pull + fused epilogues.
  pull_nodes<false><<<(NA * 64 + 255) / 256, 256, 0, stream>>>(
      h_tic, edges, rp, deg, bt, nullptr, out_ac, NA, 0);
  pull_nodes<true><<<(NW * 64 + 255) / 256, 256, 0, stream>>>(
      h_relm, edges, rp, deg, br, x_w, out_w, NW, NA);
}